// Round 7
// baseline (292.513 us; speedup 1.0000x reference)
//
#include <hip/hip_runtime.h>

#define N_NODES 50000
#define N_EDGES 500000
#define D 128
#define FXS 4194304.0f   // 2^22 fixed-point scale for weighted degree (deterministic)
#define CAP 64           // slots per node; deg ~ Poisson(10), max-deg ~30
#define GRID 512         // 2 blocks/CU on 256 CUs: co-residency with large margin
#define NT 256
#define TOT (GRID * NT)
#define NQ (N_EDGES / 4) // 125000 edge quads

typedef unsigned long long u64;

// Monotonic global barrier: counter never resets; phase k waits for k*GRID arrivals.
// Only lane 0 spins (device-scope acquire loads); __syncthreads propagates.
__device__ __forceinline__ void gbar(unsigned* bar, unsigned target) {
    __syncthreads();
    if (threadIdx.x == 0) {
        __hip_atomic_fetch_add(bar, 1u, __ATOMIC_ACQ_REL, __HIP_MEMORY_SCOPE_AGENT);
        while (__hip_atomic_load(bar, __ATOMIC_ACQUIRE, __HIP_MEMORY_SCOPE_AGENT) < target)
            __builtin_amdgcn_s_sleep(8);
    }
    __syncthreads();
}

// ONE persistent kernel, phases separated by software barriers (replaces 5 dispatches):
//  P0: per-block weight collapse into LDS (v, c1, c0) — L2-broadcast reads, no barrier
//  P1: 4-edge/thread returning-atomic bin fill  +  gemv traw[n] = x[n,:].v
//  P2: epilogue dinv/cnt/tw
//  P3: gather_s -> sw
//  P4: gather_z -> out
__global__ __launch_bounds__(NT, 2) void fused_kernel(
    const int* __restrict__ src, const int* __restrict__ dst, const float* __restrict__ ew,
    const float* __restrict__ x,
    const float* __restrict__ W1, const float* __restrict__ W2,
    const float* __restrict__ b1, const float* __restrict__ b2,
    const float* __restrict__ Wf, const float* __restrict__ bf,
    u64* __restrict__ degcnt, int2* __restrict__ pairs,
    float* __restrict__ traw, float* __restrict__ dinv, int* __restrict__ cntv,
    float* __restrict__ tw, float* __restrict__ sw, float* __restrict__ out,
    unsigned* __restrict__ bar) {
    const int t = threadIdx.x;
    const int bid = blockIdx.x;
    const int gtid = bid * NT + t;
    __shared__ float ush[D];
    __shared__ float vsh[D];
    __shared__ float csh[2];

    // ---------- P0: local weight collapse (every block; weights are L2-resident) ----------
    if (t < D) {
        float a = 0.f;
#pragma unroll 8
        for (int j = 0; j < D; ++j) a += W2[t * D + j] * Wf[j];
        ush[t] = a;                                  // u = W2 @ Wf
    }
    __syncthreads();
    if (t < D) {
        float a = 0.f;
#pragma unroll 8
        for (int k = 0; k < D; ++k) a += W1[t * D + k] * ush[k];
        vsh[t] = a;                                  // v = W1 @ u
    }
    if (t == 0) {
        float c = 0.f;
        for (int k = 0; k < D; ++k) c += b1[k] * ush[k];
        csh[0] = c;                                  // c1 = b1 . u
    } else if (t == 1) {
        float c = bf[0];
        for (int k = 0; k < D; ++k) c += b2[k] * Wf[k];
        csh[1] = c;                                  // c0 = b2 . Wf + bf
    }
    __syncthreads();

    // ---------- P1a: 4-edge/thread slot assignment + bin fill ----------
    for (int q = gtid; q < NQ; q += TOT) {
        int4   d4 = ((const int4*)dst)[q];
        int4   s4 = ((const int4*)src)[q];
        float4 w4 = ((const float4*)ew)[q];
        unsigned f0 = __float2uint_rn(w4.x * FXS);
        unsigned f1 = __float2uint_rn(w4.y * FXS);
        unsigned f2 = __float2uint_rn(w4.z * FXS);
        unsigned f3 = __float2uint_rn(w4.w * FXS);
        u64 o0 = atomicAdd(&degcnt[d4.x], (1ull << 32) | (u64)f0);
        u64 o1 = atomicAdd(&degcnt[d4.y], (1ull << 32) | (u64)f1);
        u64 o2 = atomicAdd(&degcnt[d4.z], (1ull << 32) | (u64)f2);
        u64 o3 = atomicAdd(&degcnt[d4.w], (1ull << 32) | (u64)f3);
        int s0 = (int)(o0 >> 32), s1 = (int)(o1 >> 32);
        int s2 = (int)(o2 >> 32), s3 = (int)(o3 >> 32);
        if (s0 < CAP) pairs[(size_t)d4.x * CAP + s0] = make_int2(s4.x, __float_as_int(w4.x));
        if (s1 < CAP) pairs[(size_t)d4.y * CAP + s1] = make_int2(s4.y, __float_as_int(w4.y));
        if (s2 < CAP) pairs[(size_t)d4.z * CAP + s2] = make_int2(s4.z, __float_as_int(w4.z));
        if (s3 < CAP) pairs[(size_t)d4.w * CAP + s3] = make_int2(s4.w, __float_as_int(w4.w));
    }

    // ---------- P1b: gemv traw[n] = x[n,:].v  (BW-bound; overlaps atomic latency) ----------
    {
        const int l = t & 31;
        const int sub = t >> 5;
        for (int g = bid; g < N_NODES / 8; g += GRID) {   // 6250 groups of 8 nodes
            int n = g * 8 + sub;
            float4 xv = ((const float4*)(x + (size_t)n * D))[l];
            float a = xv.x * vsh[l * 4] + xv.y * vsh[l * 4 + 1] +
                      xv.z * vsh[l * 4 + 2] + xv.w * vsh[l * 4 + 3];
#pragma unroll
            for (int off = 16; off > 0; off >>= 1) a += __shfl_xor(a, off);
            if (l == 0) traw[n] = a;
        }
    }
    gbar(bar, 1 * GRID);

    // ---------- P2: epilogue dinv/cnt/tw ----------
    for (int n = gtid; n < N_NODES; n += TOT) {
        u64 dc = degcnt[n];
        int c = (int)(dc >> 32);
        float deg = (float)(unsigned)(dc & 0xffffffffu) * (1.0f / FXS);
        float di = rsqrtf(deg + 1.0f);
        dinv[n] = di;
        cntv[n] = (c < CAP) ? c : CAP;
        tw[n] = di * traw[n];
    }
    gbar(bar, 2 * GRID);

    // ---------- P3: gather_s  sw[n] = di*( di*(sum ew*tw[src] + tw[n]) + c1 ) ----------
    {
        const int l = t & 3;
        const int sub = t >> 2;
        for (int g = bid; g < (N_NODES + 63) / 64; g += GRID) {
            int n = g * 64 + sub;
            if (n < N_NODES) {
                int cnt = cntv[n];
                const int4* row = (const int4*)(pairs + (size_t)n * CAP);
                float acc = 0.f;
                for (int c = l; 2 * c < cnt; c += 4) {
                    int4 pr = row[c];
                    acc += __int_as_float(pr.y) * tw[pr.x];
                    if (2 * c + 1 < cnt) acc += __int_as_float(pr.w) * tw[pr.z];
                }
                acc += __shfl_xor(acc, 1);
                acc += __shfl_xor(acc, 2);
                if (l == 0) {
                    float di = dinv[n];
                    sw[n] = di * (di * (acc + tw[n]) + csh[0]);
                }
            }
        }
    }
    gbar(bar, 3 * GRID);

    // ---------- P4: gather_z  out[n] = sigmoid( di*(sum ew*sw[src] + sw[n]) + c0 )*10 ----------
    {
        const int l = t & 3;
        const int sub = t >> 2;
        for (int g = bid; g < (N_NODES + 63) / 64; g += GRID) {
            int n = g * 64 + sub;
            if (n < N_NODES) {
                int cnt = cntv[n];
                const int4* row = (const int4*)(pairs + (size_t)n * CAP);
                float acc = 0.f;
                for (int c = l; 2 * c < cnt; c += 4) {
                    int4 pr = row[c];
                    acc += __int_as_float(pr.y) * sw[pr.x];
                    if (2 * c + 1 < cnt) acc += __int_as_float(pr.w) * sw[pr.z];
                }
                acc += __shfl_xor(acc, 1);
                acc += __shfl_xor(acc, 2);
                if (l == 0) {
                    float di = dinv[n];
                    float z = di * (acc + sw[n]) + csh[1];
                    out[n] = 10.0f / (1.0f + expf(-z));
                }
            }
        }
    }
}

extern "C" void kernel_launch(void* const* d_in, const int* in_sizes, int n_in,
                              void* d_out, int out_size, void* d_ws, size_t ws_size,
                              hipStream_t stream) {
    const float* x  = (const float*)d_in[0];
    const int*   ei = (const int*)d_in[1];
    const float* ew = (const float*)d_in[2];
    const float* W1 = (const float*)d_in[3];
    const float* b1 = (const float*)d_in[4];
    const float* W2 = (const float*)d_in[5];
    const float* b2 = (const float*)d_in[6];
    const float* Wf = (const float*)d_in[7];
    const float* bf = (const float*)d_in[8];
    const int* srcv = ei;
    const int* dstv = ei + N_EDGES;
    float* out = (float*)d_out;

    char* p = (char*)d_ws;
    auto alloc = [&](size_t bytes) { void* r = (void*)p; p += (bytes + 255) & ~(size_t)255; return r; };
    // zero-initialized region: barrier counter + degcnt (one small memset)
    char* zbase = p;
    unsigned* bar    = (unsigned*)alloc(256);
    u64*      degcnt = (u64*)alloc((size_t)N_NODES * 8);
    size_t zbytes = (size_t)(p - zbase);
    float* traw   = (float*)alloc(N_NODES * 4);
    float* dinv   = (float*)alloc(N_NODES * 4);
    int*   cntv   = (int*)alloc(N_NODES * 4);
    float* tw     = (float*)alloc(N_NODES * 4);
    float* sw     = (float*)alloc(N_NODES * 4);
    int2*  pairs  = (int2*)alloc((size_t)N_NODES * CAP * 8);   // 25.6 MB

    hipMemsetAsync(zbase, 0, zbytes, stream);

    fused_kernel<<<GRID, NT, 0, stream>>>(srcv, dstv, ew, x, W1, W2, b1, b2, Wf, bf,
                                          degcnt, pairs, traw, dinv, cntv, tw, sw, out,
                                          bar);
}

// Round 8
// 149.368 us; speedup vs baseline: 1.9583x; 1.9583x over previous
//
#include <hip/hip_runtime.h>

#define N_NODES 50000
#define N_EDGES 500000
#define D 128
#define CAP 64                                   // slots per node; max-deg ~35
#define NCHUNK 256                               // edge chunks (one hist/place block each)
#define EPC 1954                                 // ceil(500000/256); last chunk = 1730
#define NWORDS 12500                             // 50000 nodes / 4 per packed u32
#define SCAN_W 64                                // words per scan block (256 nodes)
#define SCAN_BLOCKS ((NWORDS + SCAN_W - 1) / SCAN_W)   // 196

// ---- P1: per-chunk dst histogram in LDS (byte-packed, no global atomics).
// Extra block (blockIdx.x == NCHUNK) computes v = W1@(W2@Wf), c1, c0 overlapped.
__global__ void hist_kernel(const int* __restrict__ dst,
                            const float* __restrict__ W1, const float* __restrict__ W2,
                            const float* __restrict__ b1, const float* __restrict__ b2,
                            const float* __restrict__ Wf, const float* __restrict__ bf,
                            unsigned* __restrict__ hist32, float* __restrict__ v,
                            float* __restrict__ consts) {
    if ((int)blockIdx.x == NCHUNK) {
        __shared__ float u[D];
        int t = threadIdx.x;
        if (t < D) {
            float a = 0.f;
#pragma unroll 8
            for (int j = 0; j < D; ++j) a += W2[t * D + j] * Wf[j];
            u[t] = a;
        }
        __syncthreads();
        if (t < D) {
            float a = 0.f;
#pragma unroll 8
            for (int k = 0; k < D; ++k) a += W1[t * D + k] * u[k];
            v[t] = a;
        }
        if (t == 0) {
            float c = 0.f;
            for (int k = 0; k < D; ++k) c += b1[k] * u[k];
            consts[0] = c;
        } else if (t == 1) {
            float c = bf[0];
            for (int k = 0; k < D; ++k) c += b2[k] * Wf[k];
            consts[1] = c;
        }
        return;
    }
    __shared__ unsigned lds[NWORDS];             // 50 KB packed u8 counters
    const int t = threadIdx.x;
    const int c = blockIdx.x;
    for (int i = t; i < NWORDS; i += 256) lds[i] = 0u;
    __syncthreads();
    const int e0 = c * EPC;
    const int e1 = (e0 + EPC < N_EDGES) ? e0 + EPC : N_EDGES;
    for (int e = e0 + t; e < e1; e += 256) {
        int d = dst[e];
        atomicAdd(&lds[d >> 2], 1u << (8 * (d & 3)));   // per-chunk count <= 35: no carry
    }
    __syncthreads();
    unsigned* outw = hist32 + (size_t)c * NWORDS;
    for (int i = t; i < NWORDS; i += 256) outw[i] = lds[i];
}

// ---- P2: transposed two-level scan. Block = 64 words (256 nodes) x all 256 chunks,
// staged in 64 KB LDS. Thread (cp, w): cp in [0,4) scans 64 chunks for word w.
// Packed-byte arithmetic throughout (deg <= 35 -> no cross-byte carries anywhere).
__global__ __launch_bounds__(256) void scan_kernel(const unsigned* __restrict__ hist32,
                                                   unsigned* __restrict__ base32,
                                                   int* __restrict__ cntv) {
    __shared__ unsigned lds[NCHUNK][SCAN_W];     // 64 KB
    __shared__ unsigned tot[4][SCAN_W];
    const int t = threadIdx.x;
    const int cp = t >> 6;                       // chunk quarter 0..3
    const int w = t & 63;                        // word within block
    const int gw = blockIdx.x * SCAN_W + w;      // global word index
    const bool valid = gw < NWORDS;
    // stage: 256 rows x 64 words, coalesced 256B per wave-instruction
    for (int cc = 0; cc < 64; ++cc) {
        int c = cp * 64 + cc;
        lds[c][w] = valid ? hist32[(size_t)c * NWORDS + gw] : 0u;
    }
    __syncthreads();
    // quarter-local exclusive prefix (in place)
    unsigned run = 0u;
    for (int cc = 0; cc < 64; ++cc) {
        int c = cp * 64 + cc;
        unsigned x = lds[c][w];
        lds[c][w] = run;
        run += x;                                // packed add, bytes <= 35
    }
    tot[cp][w] = run;
    __syncthreads();
    // cross-quarter offset (bytes <= 3*35 = 105, still no carry)
    unsigned off = 0u;
    for (int j = 0; j < cp; ++j) off += tot[j][w];
    for (int cc = 0; cc < 64; ++cc) {
        int c = cp * 64 + cc;
        lds[c][w] += off;
    }
    // node counts: total over all quarters (bytes <= 140)
    if (cp == 0 && valid) {
        unsigned tl = tot[0][w] + tot[1][w] + tot[2][w] + tot[3][w];
        int4 cv;
        cv.x = min((int)(tl & 0xffu), CAP);
        cv.y = min((int)((tl >> 8) & 0xffu), CAP);
        cv.z = min((int)((tl >> 16) & 0xffu), CAP);
        cv.w = min((int)((tl >> 24) & 0xffu), CAP);
        ((int4*)cntv)[gw] = cv;                  // NWORDS*4 == N_NODES exactly
    }
    // dump bases (each thread dumps only words it wrote: no extra sync needed)
    if (valid) {
        for (int cc = 0; cc < 64; ++cc) {
            int c = cp * 64 + cc;
            base32[(size_t)c * NWORDS + gw] = lds[c][w];
        }
    }
}

// ---- P3: placement. Block = chunk: stage its base row in LDS, slot = byte from
// returning LDS atomic (base preloaded, counts accumulate on top), write bin entry.
__global__ void place_kernel(const int* __restrict__ src, const int* __restrict__ dst,
                             const float* __restrict__ ew,
                             const unsigned* __restrict__ base32, int2* __restrict__ pairs) {
    __shared__ unsigned lds[NWORDS];             // 50 KB
    const int t = threadIdx.x;
    const int c = blockIdx.x;
    const unsigned* inw = base32 + (size_t)c * NWORDS;
    for (int i = t; i < NWORDS; i += 256) lds[i] = inw[i];
    __syncthreads();
    const int e0 = c * EPC;
    const int e1 = (e0 + EPC < N_EDGES) ? e0 + EPC : N_EDGES;
    for (int e = e0 + t; e < e1; e += 256) {
        int d = dst[e];
        int sh = 8 * (d & 3);
        unsigned old = atomicAdd(&lds[d >> 2], 1u << sh);
        int slot = (int)((old >> sh) & 0xffu);   // = global base + intra-chunk rank
        if (slot < CAP)                          // safety; never taken for this graph
            pairs[(size_t)d * CAP + slot] = make_int2(src[e], __float_as_int(ew[e]));
    }
}

// ---- gemv: 32 lanes/node, float4 loads; t[n] = x[n,:].v ; epilogue sums the node's
// own bin weights in fp32 -> deg -> dinv[n], tw[n] = dinv[n]*t[n].
__global__ void gemv_kernel(const float* __restrict__ x, const float* __restrict__ v,
                            const int2* __restrict__ pairs, const int* __restrict__ cntv,
                            float* __restrict__ dinv, float* __restrict__ tw) {
    __shared__ float vs[D];
    const int t = threadIdx.x;
    if (t < D) vs[t] = v[t];
    __syncthreads();
    const int l = t & 31;
    const int n = blockIdx.x * 8 + (t >> 5);     // 50000 = 6250*8, exact
    float4 xv = ((const float4*)(x + (size_t)n * D))[l];
    float a = xv.x * vs[l * 4] + xv.y * vs[l * 4 + 1] +
              xv.z * vs[l * 4 + 2] + xv.w * vs[l * 4 + 3];
    int cnt = cntv[n];
    const int2* row = pairs + (size_t)n * CAP;
    float wsum = 0.f;
    for (int i = l; i < cnt; i += 32) wsum += __int_as_float(row[i].y);
#pragma unroll
    for (int off = 16; off > 0; off >>= 1) {
        a    += __shfl_xor(a, off);
        wsum += __shfl_xor(wsum, off);
    }
    if (l == 0) {
        float di = rsqrtf(wsum + 1.0f);
        dinv[n] = di;
        tw[n] = di * a;
    }
}

// ---- s-pass: 4 lanes/node, int4 bin reads (2 pairs/load):
// sw[n] = dinv[n] * ( dinv[n]*(sum ew*tw[src] + tw[n]) + c1 )
__global__ void gather_s_kernel(const float* __restrict__ tw, const float* __restrict__ dinv,
                                const int* __restrict__ cntv, const int2* __restrict__ pairs,
                                const float* __restrict__ consts, float* __restrict__ sw) {
    int tid = threadIdx.x;
    int n = blockIdx.x * 64 + (tid >> 2);
    int l = tid & 3;
    if (n >= N_NODES) return;
    int cnt = cntv[n];
    const int4* row = (const int4*)(pairs + (size_t)n * CAP);
    float acc = 0.f;
    for (int c = l; 2 * c < cnt; c += 4) {
        int4 p = row[c];
        acc += __int_as_float(p.y) * tw[p.x];
        if (2 * c + 1 < cnt) acc += __int_as_float(p.w) * tw[p.z];
    }
    acc += __shfl_xor(acc, 1);
    acc += __shfl_xor(acc, 2);
    if (l == 0) {
        float di = dinv[n];
        float s = di * (acc + tw[n]) + consts[0];
        sw[n] = di * s;
    }
}

// ---- z-pass: out[n] = sigmoid( dinv[n]*(sum ew*sw[src] + sw[n]) + c0 ) * 10
__global__ void gather_z_kernel(const float* __restrict__ sw, const float* __restrict__ dinv,
                                const int* __restrict__ cntv, const int2* __restrict__ pairs,
                                const float* __restrict__ consts, float* __restrict__ out) {
    int tid = threadIdx.x;
    int n = blockIdx.x * 64 + (tid >> 2);
    int l = tid & 3;
    if (n >= N_NODES) return;
    int cnt = cntv[n];
    const int4* row = (const int4*)(pairs + (size_t)n * CAP);
    float acc = 0.f;
    for (int c = l; 2 * c < cnt; c += 4) {
        int4 p = row[c];
        acc += __int_as_float(p.y) * sw[p.x];
        if (2 * c + 1 < cnt) acc += __int_as_float(p.w) * sw[p.z];
    }
    acc += __shfl_xor(acc, 1);
    acc += __shfl_xor(acc, 2);
    if (l == 0) {
        float di = dinv[n];
        float z = di * (acc + sw[n]) + consts[1];
        out[n] = 10.0f / (1.0f + expf(-z));
    }
}

extern "C" void kernel_launch(void* const* d_in, const int* in_sizes, int n_in,
                              void* d_out, int out_size, void* d_ws, size_t ws_size,
                              hipStream_t stream) {
    const float* x  = (const float*)d_in[0];
    const int*   ei = (const int*)d_in[1];
    const float* ew = (const float*)d_in[2];
    const float* W1 = (const float*)d_in[3];
    const float* b1 = (const float*)d_in[4];
    const float* W2 = (const float*)d_in[5];
    const float* b2 = (const float*)d_in[6];
    const float* Wf = (const float*)d_in[7];
    const float* bf = (const float*)d_in[8];
    const int* srcv = ei;
    const int* dstv = ei + N_EDGES;
    float* out = (float*)d_out;

    char* p = (char*)d_ws;
    auto alloc = [&](size_t bytes) { void* r = (void*)p; p += (bytes + 255) & ~(size_t)255; return r; };
    unsigned* hist32 = (unsigned*)alloc((size_t)NCHUNK * NWORDS * 4);   // 12.8 MB
    unsigned* base32 = (unsigned*)alloc((size_t)NCHUNK * NWORDS * 4);   // 12.8 MB
    int*   cntv   = (int*)alloc(N_NODES * 4);
    float* dinv   = (float*)alloc(N_NODES * 4);
    float* tw     = (float*)alloc(N_NODES * 4);
    float* sw     = (float*)alloc(N_NODES * 4);
    float* v      = (float*)alloc(D * 4);
    float* consts = (float*)alloc(2 * 4);
    int2*  pairs  = (int2*)alloc((size_t)N_NODES * CAP * 8);   // 25.6 MB

    const int GB = (N_NODES + 63) / 64;   // 782

    // build (no global atomics, no memset)
    hist_kernel<<<NCHUNK + 1, 256, 0, stream>>>(dstv, W1, W2, b1, b2, Wf, bf,
                                                hist32, v, consts);
    scan_kernel<<<SCAN_BLOCKS, 256, 0, stream>>>(hist32, base32, cntv);
    place_kernel<<<NCHUNK, 256, 0, stream>>>(srcv, dstv, ew, base32, pairs);

    // t = x@v ; deg from own bin -> dinv, tw = dinv*t
    gemv_kernel<<<N_NODES / 8, 256, 0, stream>>>(x, v, pairs, cntv, dinv, tw);

    // two gather rounds
    gather_s_kernel<<<GB, 256, 0, stream>>>(tw, dinv, cntv, pairs, consts, sw);
    gather_z_kernel<<<GB, 256, 0, stream>>>(sw, dinv, cntv, pairs, consts, out);
}

// Round 9
// 135.803 us; speedup vs baseline: 2.1539x; 1.0999x over previous
//
#include <hip/hip_runtime.h>

#define N_NODES 50000
#define N_EDGES 500000
#define NQ (N_EDGES / 4)   // 125000 edge quads
#define D 128
#define CAP 64             // gather clamp; deg ~ Poisson(10), max ~35
#define NBUCK 98           // bucket = dst >> 9 (512 nodes per bucket)
#define BN 512             // nodes per bucket
#define REG 8192           // edge capacity per bucket region (mean 5120, sigma ~71)

// ---- prep: block 0 collapses weights (v, c1, c0); block 1 zeros bucket allocators.
__global__ void prep_kernel(const float* __restrict__ W1, const float* __restrict__ W2,
                            const float* __restrict__ b1, const float* __restrict__ b2,
                            const float* __restrict__ Wf, const float* __restrict__ bf,
                            float* __restrict__ v, float* __restrict__ consts,
                            unsigned* __restrict__ alloc) {
    const int t = threadIdx.x;
    if (blockIdx.x == 1) {
        if (t < 128) alloc[t] = 0u;
        return;
    }
    __shared__ float u[D];
    if (t < D) {
        float a = 0.f;
#pragma unroll 8
        for (int j = 0; j < D; ++j) a += W2[t * D + j] * Wf[j];
        u[t] = a;                                 // u = W2 @ Wf
    }
    __syncthreads();
    if (t < D) {
        float a = 0.f;
#pragma unroll 8
        for (int k = 0; k < D; ++k) a += W1[t * D + k] * u[k];
        v[t] = a;                                 // v = W1 @ u
    }
    if (t == 0) {
        float c = 0.f;
        for (int k = 0; k < D; ++k) c += b1[k] * u[k];
        consts[0] = c;                            // c1 = b1 . u
    } else if (t == 1) {
        float c = bf[0];
        for (int k = 0; k < D; ++k) c += b2[k] * Wf[k];
        consts[1] = c;                            // c0 = b2 . Wf + bf
    }
}

// ---- passA: partition edges into 98 dst-buckets.
// Per block: LDS histogram -> ONE returning global atomic per bucket (48K total,
// vs 500K per-edge) -> scatter (dst,src,w) 12B records into bucket regions.
__global__ void bucket_kernel(const int* __restrict__ src, const int* __restrict__ dst,
                              const float* __restrict__ ew,
                              unsigned* __restrict__ alloc, unsigned* __restrict__ recs) {
    __shared__ unsigned hist[NBUCK];              // counts, then global-base cursors
    const int t = threadIdx.x;
    if (t < NBUCK) hist[t] = 0u;
    __syncthreads();
    const int q = blockIdx.x * 256 + t;
    const bool act = q < NQ;
    int4 d4 = make_int4(0, 0, 0, 0), s4 = make_int4(0, 0, 0, 0);
    float4 w4 = make_float4(0.f, 0.f, 0.f, 0.f);
    int b0 = 0, b1 = 0, b2 = 0, b3 = 0;
    if (act) {
        d4 = ((const int4*)dst)[q];
        s4 = ((const int4*)src)[q];
        w4 = ((const float4*)ew)[q];
        b0 = d4.x >> 9; b1 = d4.y >> 9; b2 = d4.z >> 9; b3 = d4.w >> 9;
        atomicAdd(&hist[b0], 1u); atomicAdd(&hist[b1], 1u);
        atomicAdd(&hist[b2], 1u); atomicAdd(&hist[b3], 1u);
    }
    __syncthreads();
    if (t < NBUCK) hist[t] = atomicAdd(&alloc[t], hist[t]);   // run base; cursor from here
    __syncthreads();
    if (act) {
        unsigned p;
        p = atomicAdd(&hist[b0], 1u);
        if (p < REG) { size_t o = ((size_t)b0 * REG + p) * 3;
            recs[o] = (unsigned)d4.x; recs[o+1] = (unsigned)s4.x; recs[o+2] = __float_as_uint(w4.x); }
        p = atomicAdd(&hist[b1], 1u);
        if (p < REG) { size_t o = ((size_t)b1 * REG + p) * 3;
            recs[o] = (unsigned)d4.y; recs[o+1] = (unsigned)s4.y; recs[o+2] = __float_as_uint(w4.y); }
        p = atomicAdd(&hist[b2], 1u);
        if (p < REG) { size_t o = ((size_t)b2 * REG + p) * 3;
            recs[o] = (unsigned)d4.z; recs[o+1] = (unsigned)s4.z; recs[o+2] = __float_as_uint(w4.z); }
        p = atomicAdd(&hist[b3], 1u);
        if (p < REG) { size_t o = ((size_t)b3 * REG + p) * 3;
            recs[o] = (unsigned)d4.w; recs[o+1] = (unsigned)s4.w; recs[o+2] = __float_as_uint(w4.w); }
    }
}

// ---- passB: one block per bucket -> compact CSR (rows 16B-aligned).
// count (LDS atomics) -> Hillis-Steele prefix -> place via returning LDS atomics.
__global__ __launch_bounds__(512) void csr_kernel(const unsigned* __restrict__ recs,
                                                  const unsigned* __restrict__ alloc,
                                                  int2* __restrict__ csr,
                                                  unsigned* __restrict__ rowptr,
                                                  int* __restrict__ cntv) {
    __shared__ unsigned cnt[BN], pfx[BN], cur[BN];
    const int b = blockIdx.x, t = threadIdx.x;
    const int nb0 = b * BN;
    const int nnode = (N_NODES - nb0 < BN) ? (N_NODES - nb0) : BN;
    unsigned total = alloc[b];
    if (total > REG) total = REG;                 // defensive; never taken
    cnt[t] = 0u;
    __syncthreads();
    const unsigned* rb = recs + (size_t)b * REG * 3;
    for (unsigned i = t; i < total; i += 512)
        atomicAdd(&cnt[rb[i * 3] - nb0], 1u);
    __syncthreads();
    const unsigned c = cnt[t];
    const unsigned cR = (c + 1u) & ~1u;           // round rows to 2 pairs = 16B
    pfx[t] = cR;
    __syncthreads();
    for (int off = 1; off < BN; off <<= 1) {      // inclusive scan, uniform control flow
        unsigned vv = (t >= off) ? pfx[t - off] : 0u;
        __syncthreads();
        pfx[t] += vv;
        __syncthreads();
    }
    const unsigned excl = pfx[t] - cR;            // exclusive, 16B-aligned
    cur[t] = excl;
    if (t < nnode) {
        rowptr[nb0 + t] = (unsigned)(b * REG) + excl;
        cntv[nb0 + t] = (c < CAP) ? (int)c : CAP;
    }
    __syncthreads();
    for (unsigned i = t; i < total; i += 512) {
        unsigned d = rb[i * 3], s = rb[i * 3 + 1], w = rb[i * 3 + 2];
        unsigned r = atomicAdd(&cur[d - nb0], 1u);
        csr[(size_t)b * REG + r] = make_int2((int)s, (int)w);
    }
}

// ---- gemv: 32 lanes/node, float4 loads; t[n] = x[n,:].v ; weighted degree summed
// in fp32 from the node's own CSR row -> dinv[n], tw[n] = dinv[n]*t[n].
__global__ void gemv_kernel(const float* __restrict__ x, const float* __restrict__ v,
                            const int2* __restrict__ csr, const unsigned* __restrict__ rowptr,
                            const int* __restrict__ cntv,
                            float* __restrict__ dinv, float* __restrict__ tw) {
    __shared__ float vs[D];
    const int t = threadIdx.x;
    if (t < D) vs[t] = v[t];
    __syncthreads();
    const int l = t & 31;
    const int n = blockIdx.x * 8 + (t >> 5);      // 50000 = 6250*8, exact
    float4 xv = ((const float4*)(x + (size_t)n * D))[l];
    float a = xv.x * vs[l * 4] + xv.y * vs[l * 4 + 1] +
              xv.z * vs[l * 4 + 2] + xv.w * vs[l * 4 + 3];
    int cnt = cntv[n];
    const int2* row = csr + rowptr[n];
    float wsum = 0.f;
    for (int i = l; i < cnt; i += 32) wsum += __int_as_float(row[i].y);
#pragma unroll
    for (int off = 16; off > 0; off >>= 1) {
        a    += __shfl_xor(a, off);
        wsum += __shfl_xor(wsum, off);
    }
    if (l == 0) {
        float di = rsqrtf(wsum + 1.0f);
        dinv[n] = di;
        tw[n] = di * a;
    }
}

// ---- s-pass: 4 lanes/node, int4 CSR reads (2 pairs/load, rows 16B-aligned):
// sw[n] = dinv[n] * ( dinv[n]*(sum ew*tw[src] + tw[n]) + c1 )
__global__ void gather_s_kernel(const float* __restrict__ tw, const float* __restrict__ dinv,
                                const int* __restrict__ cntv, const int2* __restrict__ csr,
                                const unsigned* __restrict__ rowptr,
                                const float* __restrict__ consts, float* __restrict__ sw) {
    int tid = threadIdx.x;
    int n = blockIdx.x * 64 + (tid >> 2);
    int l = tid & 3;
    if (n >= N_NODES) return;
    int cnt = cntv[n];
    const int4* row = (const int4*)(csr + rowptr[n]);
    float acc = 0.f;
    for (int c = l; 2 * c < cnt; c += 4) {
        int4 p = row[c];
        acc += __int_as_float(p.y) * tw[p.x];
        if (2 * c + 1 < cnt) acc += __int_as_float(p.w) * tw[p.z];
    }
    acc += __shfl_xor(acc, 1);
    acc += __shfl_xor(acc, 2);
    if (l == 0) {
        float di = dinv[n];
        float s = di * (acc + tw[n]) + consts[0];
        sw[n] = di * s;
    }
}

// ---- z-pass: out[n] = sigmoid( dinv[n]*(sum ew*sw[src] + sw[n]) + c0 ) * 10
__global__ void gather_z_kernel(const float* __restrict__ sw, const float* __restrict__ dinv,
                                const int* __restrict__ cntv, const int2* __restrict__ csr,
                                const unsigned* __restrict__ rowptr,
                                const float* __restrict__ consts, float* __restrict__ out) {
    int tid = threadIdx.x;
    int n = blockIdx.x * 64 + (tid >> 2);
    int l = tid & 3;
    if (n >= N_NODES) return;
    int cnt = cntv[n];
    const int4* row = (const int4*)(csr + rowptr[n]);
    float acc = 0.f;
    for (int c = l; 2 * c < cnt; c += 4) {
        int4 p = row[c];
        acc += __int_as_float(p.y) * sw[p.x];
        if (2 * c + 1 < cnt) acc += __int_as_float(p.w) * sw[p.z];
    }
    acc += __shfl_xor(acc, 1);
    acc += __shfl_xor(acc, 2);
    if (l == 0) {
        float di = dinv[n];
        float z = di * (acc + sw[n]) + consts[1];
        out[n] = 10.0f / (1.0f + expf(-z));
    }
}

extern "C" void kernel_launch(void* const* d_in, const int* in_sizes, int n_in,
                              void* d_out, int out_size, void* d_ws, size_t ws_size,
                              hipStream_t stream) {
    const float* x  = (const float*)d_in[0];
    const int*   ei = (const int*)d_in[1];
    const float* ew = (const float*)d_in[2];
    const float* W1 = (const float*)d_in[3];
    const float* b1 = (const float*)d_in[4];
    const float* W2 = (const float*)d_in[5];
    const float* b2 = (const float*)d_in[6];
    const float* Wf = (const float*)d_in[7];
    const float* bf = (const float*)d_in[8];
    const int* srcv = ei;
    const int* dstv = ei + N_EDGES;
    float* out = (float*)d_out;

    char* p = (char*)d_ws;
    auto alloc_ws = [&](size_t bytes) { void* r = (void*)p; p += (bytes + 255) & ~(size_t)255; return r; };
    unsigned* alloc  = (unsigned*)alloc_ws(128 * 4);
    unsigned* recs   = (unsigned*)alloc_ws((size_t)NBUCK * REG * 12);  // 9.6 MB
    int2*     csr    = (int2*)alloc_ws((size_t)NBUCK * REG * 8);       // 6.4 MB
    unsigned* rowptr = (unsigned*)alloc_ws(N_NODES * 4);
    int*      cntv   = (int*)alloc_ws(N_NODES * 4);
    float*    dinv   = (float*)alloc_ws(N_NODES * 4);
    float*    tw     = (float*)alloc_ws(N_NODES * 4);
    float*    sw     = (float*)alloc_ws(N_NODES * 4);
    float*    v      = (float*)alloc_ws(D * 4);
    float*    consts = (float*)alloc_ws(2 * 4);

    const int AB = (NQ + 255) / 256;      // 489
    const int GB = (N_NODES + 63) / 64;   // 782

    // weight collapse + zero bucket allocators (no hipMemsetAsync)
    prep_kernel<<<2, 256, 0, stream>>>(W1, W2, b1, b2, Wf, bf, v, consts, alloc);

    // two-level CSR build: 48K device atomics instead of 500K
    bucket_kernel<<<AB, 256, 0, stream>>>(srcv, dstv, ew, alloc, recs);
    csr_kernel<<<NBUCK, 512, 0, stream>>>(recs, alloc, csr, rowptr, cntv);

    // t = x@v ; deg from own CSR row -> dinv, tw = dinv*t
    gemv_kernel<<<N_NODES / 8, 256, 0, stream>>>(x, v, csr, rowptr, cntv, dinv, tw);

    // two gather rounds
    gather_s_kernel<<<GB, 256, 0, stream>>>(tw, dinv, cntv, csr, rowptr, consts, sw);
    gather_z_kernel<<<GB, 256, 0, stream>>>(sw, dinv, cntv, csr, rowptr, consts, out);
}

// Round 10
// 118.806 us; speedup vs baseline: 2.4621x; 1.1431x over previous
//
#include <hip/hip_runtime.h>

#define N_NODES 50000
#define N_EDGES 500000
#define NQ (N_EDGES / 4)   // 125000 edge quads
#define D 128
#define NBUCK 196          // bucket = dst >> 8 (256 nodes per bucket)
#define BN 256             // nodes per bucket
#define REG 4096           // record capacity per bucket (mean 2551, +30 sigma)
#define FXS 4194304.0f     // 2^22 fixed-point scale for weighted degree
#define AXS 2097152.0f     // 2^21 fixed-point scale for message sums (|sum| < 1024)

typedef unsigned long long u64;

// ---- prep: block 0 collapses weights (v = W1@(W2@Wf), c1, c0); block 1 zeros alloc.
__global__ void prep_kernel(const float* __restrict__ W1, const float* __restrict__ W2,
                            const float* __restrict__ b1, const float* __restrict__ b2,
                            const float* __restrict__ Wf, const float* __restrict__ bf,
                            float* __restrict__ v, float* __restrict__ consts,
                            unsigned* __restrict__ alloc) {
    const int t = threadIdx.x;
    if (blockIdx.x == 1) {
        if (t < 256) alloc[t] = 0u;
        return;
    }
    __shared__ float u[D];
    if (t < D) {
        float a = 0.f;
#pragma unroll 8
        for (int j = 0; j < D; ++j) a += W2[t * D + j] * Wf[j];
        u[t] = a;                                 // u = W2 @ Wf
    }
    __syncthreads();
    if (t < D) {
        float a = 0.f;
#pragma unroll 8
        for (int k = 0; k < D; ++k) a += W1[t * D + k] * u[k];
        v[t] = a;                                 // v = W1 @ u
    }
    if (t == 0) {
        float c = 0.f;
        for (int k = 0; k < D; ++k) c += b1[k] * u[k];
        consts[0] = c;                            // c1 = b1 . u
    } else if (t == 1) {
        float c = bf[0];
        for (int k = 0; k < D; ++k) c += b2[k] * Wf[k];
        consts[1] = c;                            // c0 = b2 . Wf + bf
    }
}

// ---- bucket: partition edges into 196 dst-range buckets of UNSORTED 8B records.
// Per block (4096 edges): LDS histogram -> one reserving global atomic per bucket
// (~24K total, vs 500K per-edge) -> scattered 8B record writes (runs of ~21).
// Record: hi = w bits, lo = (dst&255)<<16 | src   (src < 65536 needs N_NODES < 2^16: ok)
__global__ __launch_bounds__(512) void bucket_kernel(const int* __restrict__ src,
                                                     const int* __restrict__ dst,
                                                     const float* __restrict__ ew,
                                                     unsigned* __restrict__ alloc,
                                                     u64* __restrict__ recs) {
    __shared__ unsigned hist[NBUCK];
    const int t = threadIdx.x;
    if (t < NBUCK) hist[t] = 0u;
    __syncthreads();
    const int q0 = blockIdx.x * 1024 + t;
    const int q1 = q0 + 512;
    int4 dA, sA, dB, sB; float4 wA, wB;
    const bool aA = q0 < NQ, aB = q1 < NQ;
    if (aA) {
        dA = ((const int4*)dst)[q0]; sA = ((const int4*)src)[q0]; wA = ((const float4*)ew)[q0];
        atomicAdd(&hist[dA.x >> 8], 1u); atomicAdd(&hist[dA.y >> 8], 1u);
        atomicAdd(&hist[dA.z >> 8], 1u); atomicAdd(&hist[dA.w >> 8], 1u);
    }
    if (aB) {
        dB = ((const int4*)dst)[q1]; sB = ((const int4*)src)[q1]; wB = ((const float4*)ew)[q1];
        atomicAdd(&hist[dB.x >> 8], 1u); atomicAdd(&hist[dB.y >> 8], 1u);
        atomicAdd(&hist[dB.z >> 8], 1u); atomicAdd(&hist[dB.w >> 8], 1u);
    }
    __syncthreads();
    if (t < NBUCK) hist[t] = atomicAdd(&alloc[t], hist[t]);   // run base -> block cursor
    __syncthreads();
#define PLACE(dd, ss, ww)                                                        \
    {   int bkt = (dd) >> 8;                                                     \
        unsigned p = atomicAdd(&hist[bkt], 1u);                                  \
        if (p < REG)                                                             \
            recs[(size_t)bkt * REG + p] =                                        \
                ((u64)__float_as_uint(ww) << 32) |                               \
                ((unsigned)((dd) & 255) << 16) | (unsigned)(ss);                 \
    }
    if (aA) { PLACE(dA.x, sA.x, wA.x) PLACE(dA.y, sA.y, wA.y)
              PLACE(dA.z, sA.z, wA.z) PLACE(dA.w, sA.w, wA.w) }
    if (aB) { PLACE(dB.x, sB.x, wB.x) PLACE(dB.y, sB.y, wB.y)
              PLACE(dB.z, sB.z, wB.z) PLACE(dB.w, sB.w, wB.w) }
#undef PLACE
}

// ---- gemv: 32 lanes/node, float4 loads; traw[n] = x[n,:].v  (proven R3 shape)
__global__ void gemv_kernel(const float* __restrict__ x, const float* __restrict__ v,
                            float* __restrict__ traw) {
    __shared__ float vs[D];
    const int t = threadIdx.x;
    if (t < D) vs[t] = v[t];
    __syncthreads();
    const int l = t & 31;
    const int n = blockIdx.x * 8 + (t >> 5);      // 50000 = 6250*8, exact
    float4 xv = ((const float4*)(x + (size_t)n * D))[l];
    float a = xv.x * vs[l * 4] + xv.y * vs[l * 4 + 1] +
              xv.z * vs[l * 4 + 2] + xv.w * vs[l * 4 + 3];
#pragma unroll
    for (int off = 16; off > 0; off >>= 1) a += __shfl_xor(a, off);
    if (l == 0) traw[n] = a;
}

// ---- degtw: one block per bucket. Stream records -> fixed-point weighted degree
// in LDS -> dinv[n] = rsqrt(deg+1), tw[n] = dinv[n]*traw[n].
__global__ __launch_bounds__(512) void degtw_kernel(const u64* __restrict__ recs,
                                                    const unsigned* __restrict__ alloc,
                                                    const float* __restrict__ traw,
                                                    float* __restrict__ dinv,
                                                    float* __restrict__ tw) {
    __shared__ unsigned ws[BN];
    const int b = blockIdx.x, t = threadIdx.x;
    if (t < BN) ws[t] = 0u;
    __syncthreads();
    unsigned total = alloc[b];
    if (total > REG) total = REG;
    const u64* rb = recs + (size_t)b * REG;
    for (unsigned i = t; i < total; i += 512) {
        u64 r = rb[i];
        float w = __uint_as_float((unsigned)(r >> 32));
        atomicAdd(&ws[((unsigned)r >> 16) & 0xffu], __float2uint_rn(w * FXS));
    }
    __syncthreads();
    if (t < BN) {
        int n = b * BN + t;
        if (n < N_NODES) {
            float di = rsqrtf((float)ws[t] * (1.0f / FXS) + 1.0f);
            dinv[n] = di;
            tw[n] = di * traw[n];
        }
    }
}

// ---- gather_s: one block per bucket. acc[d] += w*tw[src] in s32 fixed point (LDS),
// then sw[n] = di*( di*(acc + tw[n]) + c1 ).
__global__ __launch_bounds__(512) void gather_s_kernel(const u64* __restrict__ recs,
                                                       const unsigned* __restrict__ alloc,
                                                       const float* __restrict__ tw,
                                                       const float* __restrict__ dinv,
                                                       const float* __restrict__ consts,
                                                       float* __restrict__ sw) {
    __shared__ int acc[BN];
    const int b = blockIdx.x, t = threadIdx.x;
    if (t < BN) acc[t] = 0;
    __syncthreads();
    unsigned total = alloc[b];
    if (total > REG) total = REG;
    const u64* rb = recs + (size_t)b * REG;
    for (unsigned i = t; i < total; i += 512) {
        u64 r = rb[i];
        unsigned lo = (unsigned)r;
        float m = __uint_as_float((unsigned)(r >> 32)) * tw[lo & 0xffffu];
        atomicAdd(&acc[(lo >> 16) & 0xffu], __float2int_rn(m * AXS));
    }
    __syncthreads();
    if (t < BN) {
        int n = b * BN + t;
        if (n < N_NODES) {
            float di = dinv[n];
            float a = (float)acc[t] * (1.0f / AXS);
            sw[n] = di * (di * (a + tw[n]) + consts[0]);
        }
    }
}

// ---- gather_z: same shape; out[n] = sigmoid( di*(acc + sw[n]) + c0 ) * 10.
__global__ __launch_bounds__(512) void gather_z_kernel(const u64* __restrict__ recs,
                                                       const unsigned* __restrict__ alloc,
                                                       const float* __restrict__ sw,
                                                       const float* __restrict__ dinv,
                                                       const float* __restrict__ consts,
                                                       float* __restrict__ out) {
    __shared__ int acc[BN];
    const int b = blockIdx.x, t = threadIdx.x;
    if (t < BN) acc[t] = 0;
    __syncthreads();
    unsigned total = alloc[b];
    if (total > REG) total = REG;
    const u64* rb = recs + (size_t)b * REG;
    for (unsigned i = t; i < total; i += 512) {
        u64 r = rb[i];
        unsigned lo = (unsigned)r;
        float m = __uint_as_float((unsigned)(r >> 32)) * sw[lo & 0xffffu];
        atomicAdd(&acc[(lo >> 16) & 0xffu], __float2int_rn(m * AXS));
    }
    __syncthreads();
    if (t < BN) {
        int n = b * BN + t;
        if (n < N_NODES) {
            float di = dinv[n];
            float a = (float)acc[t] * (1.0f / AXS);
            float z = di * (a + sw[n]) + consts[1];
            out[n] = 10.0f / (1.0f + expf(-z));
        }
    }
}

extern "C" void kernel_launch(void* const* d_in, const int* in_sizes, int n_in,
                              void* d_out, int out_size, void* d_ws, size_t ws_size,
                              hipStream_t stream) {
    const float* x  = (const float*)d_in[0];
    const int*   ei = (const int*)d_in[1];
    const float* ew = (const float*)d_in[2];
    const float* W1 = (const float*)d_in[3];
    const float* b1 = (const float*)d_in[4];
    const float* W2 = (const float*)d_in[5];
    const float* b2 = (const float*)d_in[6];
    const float* Wf = (const float*)d_in[7];
    const float* bf = (const float*)d_in[8];
    const int* srcv = ei;
    const int* dstv = ei + N_EDGES;
    float* out = (float*)d_out;

    char* p = (char*)d_ws;
    auto alloc_ws = [&](size_t bytes) { void* r = (void*)p; p += (bytes + 255) & ~(size_t)255; return r; };
    unsigned* alloc  = (unsigned*)alloc_ws(256 * 4);
    u64*      recs   = (u64*)alloc_ws((size_t)NBUCK * REG * 8);   // 6.4 MB
    float*    traw   = (float*)alloc_ws(N_NODES * 4);
    float*    dinv   = (float*)alloc_ws(N_NODES * 4);
    float*    tw     = (float*)alloc_ws(N_NODES * 4);
    float*    sw     = (float*)alloc_ws(N_NODES * 4);
    float*    v      = (float*)alloc_ws(D * 4);
    float*    consts = (float*)alloc_ws(2 * 4);

    const int BB = (NQ + 1023) / 1024;    // 123 bucket blocks (4096 edges each)

    // weight collapse + zero bucket allocators (no memset dispatch)
    prep_kernel<<<2, 256, 0, stream>>>(W1, W2, b1, b2, Wf, bf, v, consts, alloc);

    // partition edges into 196 unsorted bucket regions (no per-node sort!)
    bucket_kernel<<<BB, 512, 0, stream>>>(srcv, dstv, ew, alloc, recs);

    // traw = x @ v
    gemv_kernel<<<N_NODES / 8, 256, 0, stream>>>(x, v, traw);

    // per-bucket LDS accumulation: degree -> dinv/tw, then the two layers
    degtw_kernel<<<NBUCK, 512, 0, stream>>>(recs, alloc, traw, dinv, tw);
    gather_s_kernel<<<NBUCK, 512, 0, stream>>>(recs, alloc, tw, dinv, consts, sw);
    gather_z_kernel<<<NBUCK, 512, 0, stream>>>(recs, alloc, sw, dinv, consts, out);
}